// Round 1
// baseline (497.636 us; speedup 1.0000x reference)
//
#include <hip/hip_runtime.h>
#include <math.h>

#define NB 2
#define NL 2048
#define NK 32
#define NODE_F 128
#define EDGE_F 128

// output layout (float32 elements)
#define OFF_HV   0
#define OFF_HE   (NB*NL*NODE_F)                 // 524288
#define OFF_EIDX (OFF_HE + NB*NL*NK*EDGE_F)     // 17301504
#define OFF_X    (OFF_EIDX + NB*NL*NK)          // 17432576

// ---------------- helpers ----------------
__device__ __forceinline__ void cross3(const float a[3], const float b[3], float c[3]) {
    c[0] = a[1]*b[2] - a[2]*b[1];
    c[1] = a[2]*b[0] - a[0]*b[2];
    c[2] = a[0]*b[1] - a[1]*b[0];
}
__device__ __forceinline__ float dot3(const float a[3], const float b[3]) {
    return a[0]*b[0] + a[1]*b[1] + a[2]*b[2];
}
// reference _dihedral: u0=p2-p1, u1=p0-p1, u2=p3-p2
// n1=norm(cross(u0,u1)), n2=norm(cross(u0,u2)), sgn=sign(dot(cross(u1,u2),u0))
// result = nan_to_num(sgn*acos(dot(n1,n2)))
__device__ float dihedral_f(const float p0[3], const float p1[3],
                            const float p2[3], const float p3[3]) {
    float u0[3], u1[3], u2[3];
    for (int d = 0; d < 3; d++) {
        u0[d] = p2[d] - p1[d];
        u1[d] = p0[d] - p1[d];
        u2[d] = p3[d] - p2[d];
    }
    float n1[3], n2[3], c12[3];
    cross3(u0, u1, n1);
    cross3(u0, u2, n2);
    cross3(u1, u2, c12);
    float l1 = sqrtf(dot3(n1, n1));
    float l2 = sqrtf(dot3(n2, n2));
    float cosang = dot3(n1, n2) / (l1 * l2);
    float s = dot3(c12, u0);
    float sgn = (s > 0.f) ? 1.f : ((s < 0.f) ? -1.f : 0.f);
    float r = sgn * acosf(cosang);   // acos(|x|>1) -> NaN -> nan_to_num -> 0
    return isnan(r) ? 0.f : r;
}

// ---------------- kernel 1: X5 prep (N,Ca,C,O,Cb) + X passthrough ----------------
__global__ void prep_kernel(const float* __restrict__ X, float* __restrict__ X5,
                            float* __restrict__ out) {
    int row = blockIdx.x * blockDim.x + threadIdx.x;
    if (row >= NB * NL) return;
    float v[12];
#pragma unroll
    for (int t = 0; t < 12; t++) v[t] = X[row * 12 + t];
    // passthrough output X
#pragma unroll
    for (int t = 0; t < 12; t++) out[OFF_X + row * 12 + t] = v[t];
    // Cb = -0.58273431*cross(bv,cv) + 0.56802827*bv - 0.54067466*cv + Ca
    float bv[3], cv[3], cr[3];
    for (int d = 0; d < 3; d++) { bv[d] = v[3+d] - v[d]; cv[d] = v[6+d] - v[3+d]; }
    cross3(bv, cv, cr);
    float* x5 = X5 + row * 15;
#pragma unroll
    for (int t = 0; t < 12; t++) x5[t] = v[t];
    for (int d = 0; d < 3; d++)
        x5[12 + d] = -0.58273431f * cr[d] + 0.56802827f * bv[d] - 0.54067466f * cv[d] + v[3+d];
}

// ---------------- kernel 2: KNN (top-K smallest D, tie -> lowest index) ----------------
__global__ __launch_bounds__(256) void knn_kernel(const float* __restrict__ X,
                                                  const float* __restrict__ mask,
                                                  int* __restrict__ EidxW,
                                                  float* __restrict__ out) {
    __shared__ float sCa[NL * 3];
    __shared__ float sM[NL];
    __shared__ float sD[NL];
    __shared__ unsigned long long red[256];
    __shared__ float rmax[256];
    int tid = threadIdx.x;
    int row = blockIdx.x;            // b*NL + i
    int b = row / NL, i = row % NL;

    for (int j = tid; j < NL; j += 256) {
        const float* p = X + ((size_t)(b * NL + j) * 4 + 1) * 3;  // Ca
        sCa[j * 3 + 0] = p[0];
        sCa[j * 3 + 1] = p[1];
        sCa[j * 3 + 2] = p[2];
        sM[j] = mask[b * NL + j];
    }
    __syncthreads();
    float cx = sCa[i * 3], cy = sCa[i * 3 + 1], cz = sCa[i * 3 + 2];
    float mi = sM[i];
    float lmax = 0.0f;
    // D = m2 * sqrt(dx^2+dy^2+dz^2 + 1e-6), numpy-exact associativity, no FMA contraction
    for (int j = tid; j < NL; j += 256) {
        float dx = __fsub_rn(cx, sCa[j * 3 + 0]);
        float dy = __fsub_rn(cy, sCa[j * 3 + 1]);
        float dz = __fsub_rn(cz, sCa[j * 3 + 2]);
        float ss = __fadd_rn(__fadd_rn(__fadd_rn(__fmul_rn(dx, dx), __fmul_rn(dy, dy)),
                                       __fmul_rn(dz, dz)), 1e-6f);
        float d = __fmul_rn(__fmul_rn(mi, sM[j]), __fsqrt_rn(ss));
        sD[j] = d;
        lmax = fmaxf(lmax, d);
    }
    rmax[tid] = lmax;
    __syncthreads();
    for (int s2 = 128; s2 > 0; s2 >>= 1) {
        if (tid < s2) rmax[tid] = fmaxf(rmax[tid], rmax[tid + s2]);
        __syncthreads();
    }
    float dmax = rmax[0];
    // D_adj = D + 2*(1-m2)*rowmax(D)   (exactly D when mask==1)
    for (int j = tid; j < NL; j += 256) {
        float m2 = __fmul_rn(mi, sM[j]);
        sD[j] = __fadd_rn(sD[j], __fmul_rn(__fmul_rn(2.0f, __fsub_rn(1.0f, m2)), dmax));
    }
    __syncthreads();
    // 32x packed (dist,idx) argmin; float bits monotone for d>=0
    for (int k = 0; k < NK; k++) {
        unsigned long long best = 0xFFFFFFFFFFFFFFFFull;
        for (int j = tid; j < NL; j += 256) {
            unsigned long long cand =
                (((unsigned long long)__float_as_uint(sD[j])) << 32) | (unsigned)j;
            if (cand < best) best = cand;
        }
        red[tid] = best;
        __syncthreads();
        for (int s2 = 128; s2 > 0; s2 >>= 1) {
            if (tid < s2) { if (red[tid + s2] < red[tid]) red[tid] = red[tid + s2]; }
            __syncthreads();
        }
        if (tid == 0) {
            int widx = (int)(red[0] & 0xFFFFFFFFull);
            EidxW[row * NK + k] = widx;
            out[OFF_EIDX + row * NK + k] = (float)widx;
            sD[widx] = __int_as_float(0x7F800000);  // +inf: remove from later rounds
        }
        __syncthreads();
    }
}

// ---------------- kernel 3: node features + LN ----------------
__global__ __launch_bounds__(128) void node_kernel(const int* __restrict__ S,
                                                   const float* __restrict__ BB,
                                                   const float* __restrict__ SC,
                                                   const float* __restrict__ Wn,
                                                   const float* __restrict__ bn,
                                                   const float* __restrict__ gn,
                                                   const float* __restrict__ betan,
                                                   float* __restrict__ out) {
    int row = blockIdx.x;
    int f = threadIdx.x;
    float acc = bn[f] + Wn[S[row] * NODE_F + f];
#pragma unroll
    for (int t = 0; t < 6; t++) acc += BB[row * 6 + t] * Wn[(21 + t) * NODE_F + f];
#pragma unroll
    for (int t = 0; t < 8; t++) acc += SC[row * 8 + t] * Wn[(27 + t) * NODE_F + f];
    __shared__ float r[128];
    r[f] = acc;
    __syncthreads();
    for (int s = 64; s > 0; s >>= 1) {
        if (f < s) r[f] += r[f + s];
        __syncthreads();
    }
    float mean = r[0] * (1.0f / 128.0f);
    __syncthreads();
    float d = acc - mean;
    r[f] = d * d;
    __syncthreads();
    for (int s = 64; s > 0; s >>= 1) {
        if (f < s) r[f] += r[f + s];
        __syncthreads();
    }
    float var = r[0] * (1.0f / 128.0f);
    out[OFF_HV + row * NODE_F + f] = d * (1.0f / sqrtf(var + 1e-5f)) * gn[f] + betan[f];
}

// ---------------- kernel 4: fused edge features + GEMM + LN ----------------
// block = 64 edges (2 residues x K=32), 256 threads
// thread tile: 4 edges x 8 features; K-loop over 25 atom-pairs x 16 RBFs
__global__ __launch_bounds__(256) void edge_kernel(const float* __restrict__ X5,
                                                   const int* __restrict__ Eidx,
                                                   const int* __restrict__ chain,
                                                   const float* __restrict__ We,
                                                   const float* __restrict__ be,
                                                   const float* __restrict__ ge,
                                                   const float* __restrict__ betae,
                                                   float* __restrict__ out) {
    __shared__ float sXi[2][15];
    __shared__ float sXj[64][16];
    __shared__ int sJ[64];
    __shared__ int sPos[64];
    __shared__ float sEt[64], sPhi[64], sPsi[64];
    __shared__ float sDn[25][64];
    __shared__ __attribute__((aligned(16))) float sWb[16 * 128];
    __shared__ __attribute__((aligned(16))) float sRbf[16][64];
    __shared__ float sP1[64][16];
    __shared__ float sP2[64][16];
    __shared__ float sMean[64], sRstd[64];

    int tid = threadIdx.x;
    int e0 = blockIdx.x * 64;
    int b = e0 / (NL * NK);
    int i0 = (e0 / NK) % NL;  // covers residues i0, i0+1

    if (tid < 64) sJ[tid] = Eidx[e0 + tid];
    if (tid < 30) sXi[tid / 15][tid % 15] = X5[(b * NL + i0 + tid / 15) * 15 + (tid % 15)];
    __syncthreads();
    for (int t = tid; t < 64 * 15; t += 256) {
        int e = t / 15, c = t % 15;
        sXj[e][c] = X5[(b * NL + sJ[e]) * 15 + c];
    }
    if (tid < 64) {
        int e = tid;
        int i = i0 + (e >> 5);
        int j = sJ[e];
        int off = j - i + 32;
        off = off < 0 ? 0 : (off > 64 ? 64 : off);
        sPos[e] = off;
        sEt[e] = (chain[b * NL + j] == chain[b * NL + i]) ? 2.0f : 1.0f;
    }
    __syncthreads();
    // 25 pairwise atom distances per edge
    for (int t = tid; t < 1600; t += 256) {
        int p = t >> 6, e = t & 63;
        int a = p / 5, c = p - a * 5;
        const float* xi = &sXi[e >> 5][a * 3];
        const float* xj = &sXj[e][c * 3];
        float dx = xi[0] - xj[0], dy = xi[1] - xj[1], dz = xi[2] - xj[2];
        sDn[p][e] = sqrtf(dx * dx + dy * dy + dz * dz + 1e-6f);
    }
    // dihedrals (one thread per edge)
    if (tid < 64) {
        int e = tid;
        const float* xi = sXi[e >> 5];
        const float* xj = sXj[e];
        sPhi[e] = dihedral_f(&xi[6], &xj[0], &xj[3], &xj[6]);  // (C_i, N_j, Ca_j, C_j)
        sPsi[e] = dihedral_f(&xi[0], &xi[3], &xi[6], &xj[0]);  // (N_i, Ca_i, C_i, N_j)
    }
    __syncthreads();

    int eg = tid & 15;   // edges eg*4 .. eg*4+3
    int fg = tid >> 4;   // features fg*8 .. +7
    int f0 = fg * 8;
    float acc[4][8];
    // fold one-hot position row, chain-type row, dihedral rows and bias into init
#pragma unroll
    for (int ee = 0; ee < 4; ee++) {
        int e = eg * 4 + ee;
        float et = sEt[e], ph = sPhi[e], ps = sPsi[e];
        const float* wpos = We + sPos[e] * 128 + f0;
        const float* wt = We + 465 * 128 + f0;
        const float* wph = We + 466 * 128 + f0;
        const float* wps = We + 467 * 128 + f0;
#pragma unroll
        for (int ff = 0; ff < 8; ff++)
            acc[ee][ff] = be[f0 + ff] + wpos[ff] + et * wt[ff] + ph * wph[ff] + ps * wps[ff];
    }

    // GEMM over 400 RBF dims in 25 chunks of 16
    for (int p = 0; p < 25; p++) {
        __syncthreads();
        {   // stage W rows 65+p*16 .. +15 (16x128)
            const float4* src = (const float4*)(We + (65 + p * 16) * 128);
            float4* dst = (float4*)sWb;
            for (int t = tid; t < 512; t += 256) dst[t] = src[t];
        }
        {   // compute RBF chunk: rbf[r][e] = exp(-(((d - mu_r)/1.25)^2)
            int v = tid * 4;
            int kk = v >> 6;
            int e = v & 63;
            float mu = (float)kk * (20.0f / 15.0f);
#pragma unroll
            for (int u = 0; u < 4; u++) {
                float d = sDn[p][e + u];
                float x = (d - mu) * (1.0f / 1.25f);
                sRbf[kk][e + u] = expf(-x * x);
            }
        }
        __syncthreads();
#pragma unroll
        for (int kk = 0; kk < 16; kk++) {
            const float4 a4 = *(const float4*)&sRbf[kk][eg * 4];
            const float4 w0 = *(const float4*)&sWb[kk * 128 + f0];
            const float4 w1 = *(const float4*)&sWb[kk * 128 + f0 + 4];
            const float av[4] = {a4.x, a4.y, a4.z, a4.w};
            const float wv[8] = {w0.x, w0.y, w0.z, w0.w, w1.x, w1.y, w1.z, w1.w};
#pragma unroll
            for (int ee = 0; ee < 4; ee++)
#pragma unroll
                for (int ff = 0; ff < 8; ff++)
                    acc[ee][ff] = fmaf(av[ee], wv[ff], acc[ee][ff]);
        }
    }

    // fused LayerNorm over 128 features per edge
    __syncthreads();
#pragma unroll
    for (int ee = 0; ee < 4; ee++) {
        float s = 0.f, q = 0.f;
#pragma unroll
        for (int ff = 0; ff < 8; ff++) { s += acc[ee][ff]; q += acc[ee][ff] * acc[ee][ff]; }
        sP1[eg * 4 + ee][fg] = s;
        sP2[eg * 4 + ee][fg] = q;
    }
    __syncthreads();
    if (tid < 64) {
        float s = 0.f, q = 0.f;
#pragma unroll
        for (int t = 0; t < 16; t++) { s += sP1[tid][t]; q += sP2[tid][t]; }
        float mean = s * (1.0f / 128.0f);
        float var = q * (1.0f / 128.0f) - mean * mean;
        sMean[tid] = mean;
        sRstd[tid] = 1.0f / sqrtf(var + 1e-5f);
    }
    __syncthreads();
#pragma unroll
    for (int ee = 0; ee < 4; ee++) {
        int e = eg * 4 + ee;
        float mu = sMean[e], rs = sRstd[e];
        float o[8];
#pragma unroll
        for (int ff = 0; ff < 8; ff++)
            o[ff] = (acc[ee][ff] - mu) * rs * ge[f0 + ff] + betae[f0 + ff];
        float4* dst = (float4*)(out + OFF_HE + (size_t)(e0 + e) * 128 + f0);
        dst[0] = make_float4(o[0], o[1], o[2], o[3]);
        dst[1] = make_float4(o[4], o[5], o[6], o[7]);
    }
}

// ---------------- launch ----------------
extern "C" void kernel_launch(void* const* d_in, const int* in_sizes, int n_in,
                              void* d_out, int out_size, void* d_ws, size_t ws_size,
                              hipStream_t stream) {
    (void)in_sizes; (void)n_in; (void)out_size; (void)ws_size;
    const float* X    = (const float*)d_in[0];
    const int*   S    = (const int*)d_in[1];
    const float* BB   = (const float*)d_in[2];
    const float* SC   = (const float*)d_in[3];
    const int*   chain= (const int*)d_in[4];
    const float* mask = (const float*)d_in[5];
    const float* Wn   = (const float*)d_in[6];
    const float* bn   = (const float*)d_in[7];
    const float* gn   = (const float*)d_in[8];
    const float* betan= (const float*)d_in[9];
    const float* We   = (const float*)d_in[10];
    const float* be   = (const float*)d_in[11];
    const float* ge   = (const float*)d_in[12];
    const float* betae= (const float*)d_in[13];
    float* out = (float*)d_out;

    int*   EidxW = (int*)d_ws;                       // NB*NL*NK ints
    float* X5    = (float*)d_ws + (NB * NL * NK);    // NB*NL*15 floats

    hipLaunchKernelGGL(prep_kernel, dim3((NB * NL + 255) / 256), dim3(256), 0, stream,
                       X, X5, out);
    hipLaunchKernelGGL(knn_kernel, dim3(NB * NL), dim3(256), 0, stream,
                       X, mask, EidxW, out);
    hipLaunchKernelGGL(node_kernel, dim3(NB * NL), dim3(128), 0, stream,
                       S, BB, SC, Wn, bn, gn, betan, out);
    hipLaunchKernelGGL(edge_kernel, dim3(NB * NL * NK / 64), dim3(256), 0, stream,
                       X5, EidxW, chain, We, be, ge, betae, out);
}

// Round 2
// 227.123 us; speedup vs baseline: 2.1910x; 2.1910x over previous
//
#include <hip/hip_runtime.h>
#include <math.h>

#define NB 2
#define NL 2048
#define NK 32
#define NODE_F 128
#define EDGE_F 128

// output layout (float32 elements)
#define OFF_HV   0
#define OFF_HE   (NB*NL*NODE_F)                 // 524288
#define OFF_EIDX (OFF_HE + NB*NL*NK*EDGE_F)     // 17301504
#define OFF_X    (OFF_EIDX + NB*NL*NK)          // 17432576

typedef __attribute__((ext_vector_type(8))) short v8s;
typedef __attribute__((ext_vector_type(4))) float v4f;

__device__ __forceinline__ short f2bf(float f) {
    unsigned u = __float_as_uint(f);
    unsigned r = u + 0x7fffu + ((u >> 16) & 1u);
    return (short)(r >> 16);
}

// ---------------- helpers ----------------
__device__ __forceinline__ void cross3(const float a[3], const float b[3], float c[3]) {
    c[0] = a[1]*b[2] - a[2]*b[1];
    c[1] = a[2]*b[0] - a[0]*b[2];
    c[2] = a[0]*b[1] - a[1]*b[0];
}
__device__ __forceinline__ float dot3(const float a[3], const float b[3]) {
    return a[0]*b[0] + a[1]*b[1] + a[2]*b[2];
}
__device__ float dihedral_f(const float p0[3], const float p1[3],
                            const float p2[3], const float p3[3]) {
    float u0[3], u1[3], u2[3];
    for (int d = 0; d < 3; d++) {
        u0[d] = p2[d] - p1[d];
        u1[d] = p0[d] - p1[d];
        u2[d] = p3[d] - p2[d];
    }
    float n1[3], n2[3], c12[3];
    cross3(u0, u1, n1);
    cross3(u0, u2, n2);
    cross3(u1, u2, c12);
    float l1 = sqrtf(dot3(n1, n1));
    float l2 = sqrtf(dot3(n2, n2));
    float cosang = dot3(n1, n2) / (l1 * l2);
    float s = dot3(c12, u0);
    float sgn = (s > 0.f) ? 1.f : ((s < 0.f) ? -1.f : 0.f);
    float r = sgn * acosf(cosang);
    return isnan(r) ? 0.f : r;
}

// ---------------- kernel 0: W_edge RBF rows -> bf16 MFMA-fragment order ----------------
// WTf layout: [chunk 13][nt 8][lane 64][j 8] bf16; B[k][n]: n = nt*16 + (lane&15),
// k = chunk*32 + (lane>>4)*8 + j  (k >= 400 zero-padded)
__global__ void wconv_kernel(const float* __restrict__ We, short* __restrict__ WTf) {
    int t = blockIdx.x * 256 + threadIdx.x;
    if (t >= 13 * 8 * 64) return;
    int lane = t & 63;
    int nt = (t >> 6) & 7;
    int ch = t >> 9;
    int n = nt * 16 + (lane & 15);
    int kbase = ch * 32 + (lane >> 4) * 8;
    short* dst = WTf + (size_t)t * 8;
#pragma unroll
    for (int j = 0; j < 8; j++) {
        int k = kbase + j;
        float f = (k < 400) ? We[(65 + k) * 128 + n] : 0.f;
        dst[j] = f2bf(f);
    }
}

// ---------------- kernel 1: X5 prep (N,Ca,C,O,Cb) + X passthrough ----------------
__global__ void prep_kernel(const float* __restrict__ X, float* __restrict__ X5,
                            float* __restrict__ out) {
    int row = blockIdx.x * blockDim.x + threadIdx.x;
    if (row >= NB * NL) return;
    float v[12];
#pragma unroll
    for (int t = 0; t < 12; t++) v[t] = X[row * 12 + t];
#pragma unroll
    for (int t = 0; t < 12; t++) out[OFF_X + row * 12 + t] = v[t];
    float bv[3], cv[3], cr[3];
    for (int d = 0; d < 3; d++) { bv[d] = v[3+d] - v[d]; cv[d] = v[6+d] - v[3+d]; }
    cross3(bv, cv, cr);
    float* x5 = X5 + row * 15;
#pragma unroll
    for (int t = 0; t < 12; t++) x5[t] = v[t];
    for (int d = 0; d < 3; d++)
        x5[12 + d] = -0.58273431f * cr[d] + 0.56802827f * bv[d] - 0.54067466f * cv[d] + v[3+d];
}

// ---------------- kernel 2: KNN — one wave per row, register-resident selection ----------------
__global__ __launch_bounds__(256) void knn2_kernel(const float* __restrict__ X,
                                                   const float* __restrict__ mask,
                                                   int* __restrict__ EidxW,
                                                   float* __restrict__ out) {
    __shared__ float sCa[NL * 3];
    __shared__ float sM[NL];
    int tid = threadIdx.x;
    int i0 = blockIdx.x * 4;          // 4 rows per block (one per wave), same batch
    int b = i0 / NL;
    for (int j = tid; j < NL; j += 256) {
        const float* p = X + ((size_t)(b * NL + j) * 4 + 1) * 3;  // Ca
        sCa[j * 3 + 0] = p[0];
        sCa[j * 3 + 1] = p[1];
        sCa[j * 3 + 2] = p[2];
        sM[j] = mask[b * NL + j];
    }
    __syncthreads();
    int w = tid >> 6, l = tid & 63;
    int iloc = i0 - b * NL + w;
    float cx = sCa[iloc * 3], cy = sCa[iloc * 3 + 1], cz = sCa[iloc * 3 + 2];
    float mi = sM[iloc];

    // numpy-exact distances (no FMA contraction), 32 per lane
    float dreg[32];
    float lmax = 0.0f;
#pragma unroll
    for (int t = 0; t < 32; t++) {
        int j = t * 64 + l;
        float dx = __fsub_rn(cx, sCa[j * 3 + 0]);
        float dy = __fsub_rn(cy, sCa[j * 3 + 1]);
        float dz = __fsub_rn(cz, sCa[j * 3 + 2]);
        float ss = __fadd_rn(__fadd_rn(__fadd_rn(__fmul_rn(dx, dx), __fmul_rn(dy, dy)),
                                       __fmul_rn(dz, dz)), 1e-6f);
        float d = __fmul_rn(__fmul_rn(mi, sM[j]), __fsqrt_rn(ss));
        dreg[t] = d;
        lmax = fmaxf(lmax, d);
    }
#pragma unroll
    for (int s = 1; s < 64; s <<= 1) lmax = fmaxf(lmax, __shfl_xor(lmax, s, 64));

    // packed (dist_bits, idx) keys: ascending u64 order == (dist asc, idx asc)
    unsigned long long key[32];
#pragma unroll
    for (int t = 0; t < 32; t++) {
        int j = t * 64 + l;
        float m2 = __fmul_rn(mi, sM[j]);
        float dadj = __fadd_rn(dreg[t],
                     __fmul_rn(__fmul_rn(2.0f, __fsub_rn(1.0f, m2)), lmax));
        key[t] = (((unsigned long long)__float_as_uint(dadj)) << 32) | (unsigned)j;
    }

    int row = i0 + w;
    for (int r = 0; r < NK; r++) {
        unsigned long long best = 0xFFFFFFFFFFFFFFFFull;
#pragma unroll
        for (int t = 0; t < 32; t++) best = (key[t] < best) ? key[t] : best;
#pragma unroll
        for (int s = 1; s < 64; s <<= 1) {
            unsigned hi = __shfl_xor((unsigned)(best >> 32), s, 64);
            unsigned lo = __shfl_xor((unsigned)(best & 0xFFFFFFFFu), s, 64);
            unsigned long long o = (((unsigned long long)hi) << 32) | lo;
            best = (o < best) ? o : best;
        }
        if (l == 0) {
            int widx = (int)(best & 0xFFFFFFFFull);
            EidxW[row * NK + r] = widx;
            out[OFF_EIDX + row * NK + r] = (float)widx;
        }
#pragma unroll
        for (int t = 0; t < 32; t++)
            if (key[t] == best) key[t] = 0xFFFFFFFFFFFFFFFFull;
    }
}

// ---------------- kernel 3: node features + LN ----------------
__global__ __launch_bounds__(128) void node_kernel(const int* __restrict__ S,
                                                   const float* __restrict__ BB,
                                                   const float* __restrict__ SC,
                                                   const float* __restrict__ Wn,
                                                   const float* __restrict__ bn,
                                                   const float* __restrict__ gn,
                                                   const float* __restrict__ betan,
                                                   float* __restrict__ out) {
    int row = blockIdx.x;
    int f = threadIdx.x;
    float acc = bn[f] + Wn[S[row] * NODE_F + f];
#pragma unroll
    for (int t = 0; t < 6; t++) acc += BB[row * 6 + t] * Wn[(21 + t) * NODE_F + f];
#pragma unroll
    for (int t = 0; t < 8; t++) acc += SC[row * 8 + t] * Wn[(27 + t) * NODE_F + f];
    __shared__ float r[128];
    r[f] = acc;
    __syncthreads();
    for (int s = 64; s > 0; s >>= 1) {
        if (f < s) r[f] += r[f + s];
        __syncthreads();
    }
    float mean = r[0] * (1.0f / 128.0f);
    __syncthreads();
    float d = acc - mean;
    r[f] = d * d;
    __syncthreads();
    for (int s = 64; s > 0; s >>= 1) {
        if (f < s) r[f] += r[f + s];
        __syncthreads();
    }
    float var = r[0] * (1.0f / 128.0f);
    out[OFF_HV + row * NODE_F + f] = d * (1.0f / sqrtf(var + 1e-5f)) * gn[f] + betan[f];
}

// ---------------- kernel 4: fused edge features + bf16 MFMA GEMM + LN ----------------
// block = 64 edges, 256 threads = 4 waves; wave w owns edge m-tile w*16..w*16+15.
// K = 25 pairs x 16 RBF = 400, padded to 416 = 13 chunks of 32.
__global__ __launch_bounds__(256) void edge2_kernel(const float* __restrict__ X5,
                                                    const int* __restrict__ Eidx,
                                                    const int* __restrict__ chain,
                                                    const float* __restrict__ We,
                                                    const float* __restrict__ be,
                                                    const float* __restrict__ ge,
                                                    const float* __restrict__ betae,
                                                    const short* __restrict__ WTf,
                                                    float* __restrict__ out) {
    __shared__ float sXi[2][15];
    __shared__ float sXj[64][16];
    __shared__ int sJ[64];
    __shared__ int sPos[64];
    __shared__ float sEt[64], sPhi[64], sPsi[64];
    __shared__ float sDn[25][64];
    __shared__ __attribute__((aligned(16))) short sW[4096];  // 8KB frag tile (one K-chunk)
    __shared__ float sRow[6][128];  // We[465..467], be, ge, betae

    int tid = threadIdx.x;
    int e0 = blockIdx.x * 64;
    int b = e0 / (NL * NK);
    int i0 = (e0 / NK) % NL;

    if (tid < 64) sJ[tid] = Eidx[e0 + tid];
    if (tid < 30) sXi[tid / 15][tid % 15] = X5[(b * NL + i0 + tid / 15) * 15 + (tid % 15)];
    for (int t = tid; t < 6 * 128; t += 256) {
        int rr = t >> 7, n2 = t & 127;
        float v;
        if (rr < 3) v = We[(465 + rr) * 128 + n2];
        else if (rr == 3) v = be[n2];
        else if (rr == 4) v = ge[n2];
        else v = betae[n2];
        sRow[rr][n2] = v;
    }
    __syncthreads();
    for (int t = tid; t < 64 * 15; t += 256) {
        int e = t / 15, c2 = t % 15;
        sXj[e][c2] = X5[(b * NL + sJ[e]) * 15 + c2];
    }
    if (tid < 64) {
        int e = tid;
        int i = i0 + (e >> 5);
        int j = sJ[e];
        int off = j - i + 32;
        off = off < 0 ? 0 : (off > 64 ? 64 : off);
        sPos[e] = off;
        sEt[e] = (chain[b * NL + j] == chain[b * NL + i]) ? 2.0f : 1.0f;
    }
    __syncthreads();
    for (int t = tid; t < 1600; t += 256) {
        int p = t >> 6, e = t & 63;
        int a = p / 5, c2 = p - a * 5;
        const float* xi = &sXi[e >> 5][a * 3];
        const float* xj = &sXj[e][c2 * 3];
        float dx = xi[0] - xj[0], dy = xi[1] - xj[1], dz = xi[2] - xj[2];
        sDn[p][e] = sqrtf(dx * dx + dy * dy + dz * dz + 1e-6f);
    }
    if (tid < 64) {
        int e = tid;
        const float* xi = sXi[e >> 5];
        const float* xj = sXj[e];
        sPhi[e] = dihedral_f(&xi[6], &xj[0], &xj[3], &xj[6]);
        sPsi[e] = dihedral_f(&xi[0], &xi[3], &xi[6], &xj[0]);
    }
    // prefetch W chunk 0 into registers
    const int4* gsrc = (const int4*)WTf;          // 13 chunks x 512 int4
    int4 r0 = gsrc[tid], r1 = gsrc[tid + 256];
    __syncthreads();   // features ready; sW safe to write

    int lane = tid & 63, w = tid >> 6;
    int c = lane & 15, kq = lane >> 4;
    int eA = w * 16 + c;            // A-operand row (edge) for this lane
    v4f acc[8];
#pragma unroll
    for (int nt = 0; nt < 8; nt++) acc[nt] = (v4f){0.f, 0.f, 0.f, 0.f};

    int4* sW4 = (int4*)sW;
    for (int ch = 0; ch < 13; ch++) {
        sW4[tid] = r0;
        sW4[tid + 256] = r1;
        __syncthreads();
        if (ch < 12) {
            r0 = gsrc[(ch + 1) * 512 + tid];
            r1 = gsrc[(ch + 1) * 512 + tid + 256];
        }
        // A fragment: A[m=lane&15][k=kq*8+j]; k -> pair 2ch+(kq>>1), rbf dim (kq&1)*8+j
        int pair = 2 * ch + (kq >> 1);
        float d = sDn[pair < 25 ? pair : 24][eA];
        v8s a;
#pragma unroll
        for (int j = 0; j < 8; j++) {
            float mu = (float)((kq & 1) * 8 + j) * (20.0f / 15.0f);
            float x = (d - mu) * 0.8f;
            float rv = (pair < 25) ? __expf(-x * x) : 0.f;
            a[j] = f2bf(rv);
        }
#pragma unroll
        for (int nt = 0; nt < 8; nt++) {
            v8s bfr = *(const v8s*)(sW + ((nt * 64 + lane) << 3));
            acc[nt] = __builtin_amdgcn_mfma_f32_16x16x32_bf16(a, bfr, acc[nt], 0, 0, 0);
        }
        __syncthreads();   // before next chunk overwrites sW
    }

    // epilogue: C/D layout col n = nt*16 + (lane&15), row m = kq*4 + r
#pragma unroll
    for (int r = 0; r < 4; r++) {
        int m = kq * 4 + r;
        int e = w * 16 + m;
        float ph = sPhi[e], ps = sPsi[e], et = sEt[e];
        int pos = sPos[e];
        float vals[8];
        float s = 0.f, q2 = 0.f;
#pragma unroll
        for (int nt = 0; nt < 8; nt++) {
            int n = nt * 16 + c;
            float v = acc[nt][r] + sRow[3][n] + We[pos * 128 + n]
                    + et * sRow[0][n] + ph * sRow[1][n] + ps * sRow[2][n];
            vals[nt] = v;
            s += v;
            q2 += v * v;
        }
#pragma unroll
        for (int s2 = 1; s2 < 16; s2 <<= 1) {
            s  += __shfl_xor(s,  s2, 64);
            q2 += __shfl_xor(q2, s2, 64);
        }
        float mean = s * (1.0f / 128.0f);
        float var = q2 * (1.0f / 128.0f) - mean * mean;
        float rstd = rsqrtf(var + 1e-5f);
#pragma unroll
        for (int nt = 0; nt < 8; nt++) {
            int n = nt * 16 + c;
            out[OFF_HE + (size_t)(e0 + e) * 128 + n] =
                (vals[nt] - mean) * rstd * sRow[4][n] + sRow[5][n];
        }
    }
}

// ---------------- launch ----------------
extern "C" void kernel_launch(void* const* d_in, const int* in_sizes, int n_in,
                              void* d_out, int out_size, void* d_ws, size_t ws_size,
                              hipStream_t stream) {
    (void)in_sizes; (void)n_in; (void)out_size; (void)ws_size;
    const float* X    = (const float*)d_in[0];
    const int*   S    = (const int*)d_in[1];
    const float* BB   = (const float*)d_in[2];
    const float* SC   = (const float*)d_in[3];
    const int*   chain= (const int*)d_in[4];
    const float* mask = (const float*)d_in[5];
    const float* Wn   = (const float*)d_in[6];
    const float* bn   = (const float*)d_in[7];
    const float* gn   = (const float*)d_in[8];
    const float* betan= (const float*)d_in[9];
    const float* We   = (const float*)d_in[10];
    const float* be   = (const float*)d_in[11];
    const float* ge   = (const float*)d_in[12];
    const float* betae= (const float*)d_in[13];
    float* out = (float*)d_out;

    char* ws = (char*)d_ws;
    int*   EidxW = (int*)ws;                                  // 524288 B
    float* X5    = (float*)(ws + 524288);                     // 245760 B
    short* WTf   = (short*)(ws + 524288 + 245760);            // 106496 B (16B aligned)

    hipLaunchKernelGGL(wconv_kernel, dim3(26), dim3(256), 0, stream, We, WTf);
    hipLaunchKernelGGL(prep_kernel, dim3((NB * NL + 255) / 256), dim3(256), 0, stream,
                       X, X5, out);
    hipLaunchKernelGGL(knn2_kernel, dim3(NB * NL / 4), dim3(256), 0, stream,
                       X, mask, EidxW, out);
    hipLaunchKernelGGL(node_kernel, dim3(NB * NL), dim3(128), 0, stream,
                       S, BB, SC, Wn, bn, gn, betan, out);
    hipLaunchKernelGGL(edge2_kernel, dim3(NB * NL * NK / 64), dim3(256), 0, stream,
                       X5, EidxW, chain, We, be, ge, betae, WTf, out);
}